// Round 4
// baseline (70.702 us; speedup 1.0000x reference)
//
#include <hip/hip_runtime.h>
#include <hip/hip_bf16.h>
#include <math.h>

#define N_ROWS 8192
#define M_ROWS 4096
#define DDIM   512
#define SDIM   16

#define BM 128
#define BN 128
#define BK 64
#define NT (DDIM / BK)   // 8 K-tiles

typedef __attribute__((ext_vector_type(8))) __bf16 bf16x8;
typedef __attribute__((ext_vector_type(4))) float f32x4;

__device__ __forceinline__ unsigned short f2bf_rne(float f) {
  unsigned u = __float_as_uint(f);
  u += 0x7fffu + ((u >> 16) & 1u);
  return (unsigned short)(u >> 16);
}

__device__ __forceinline__ void load_lds16(const void* g, void* l) {
  __builtin_amdgcn_global_load_lds(
      (const __attribute__((address_space(1))) void*)g,
      (__attribute__((address_space(3))) void*)l, 16, 0, 0);
}

__global__ __launch_bounds__(256) void prep_kernel(
    const float* __restrict__ x, const float* __restrict__ y,
    const float* __restrict__ samp_x, const float* __restrict__ samp_y,
    const float* __restrict__ scale,
    ushort* __restrict__ xb, ushort* __restrict__ yb,
    float* __restrict__ sqx, float* __restrict__ sqy,
    float* __restrict__ ssx, float* __restrict__ ssy)
{
  int row = blockIdx.x;
  const float* src; const float* samp; ushort* dst; float* sqo; float* sso;
  if (row < N_ROWS) {
    src = x + (size_t)row * DDIM; samp = samp_x + (size_t)row * SDIM;
    dst = xb + (size_t)row * DDIM; sqo = sqx + row; sso = ssx + row;
  } else {
    int r = row - N_ROWS;
    src = y + (size_t)r * DDIM; samp = samp_y + (size_t)r * SDIM;
    dst = yb + (size_t)r * DDIM; sqo = sqy + r; sso = ssy + r;
  }
  int tid = threadIdx.x;  // 256 threads, 2 f32 each
  float2 v = ((const float2*)src)[tid];
  ushort2 b;
  b.x = f2bf_rne(v.x);
  b.y = f2bf_rne(v.y);
  ((ushort2*)dst)[tid] = b;
  float ss = v.x * v.x + v.y * v.y;
  #pragma unroll
  for (int off = 32; off > 0; off >>= 1) ss += __shfl_down(ss, off, 64);
  __shared__ float red[4];
  if ((tid & 63) == 0) red[tid >> 6] = ss;
  __syncthreads();
  if (tid == 0) {
    float tot = red[0] + red[1] + red[2] + red[3];
    *sqo = tot;
    float acc = 0.f;
    #pragma unroll
    for (int s = 0; s < SDIM; s++) acc += samp[s] * scale[s];
    float sp = (acc > 15.f) ? acc : log1pf(expf(acc));   // softplus
    sp = fminf(fmaxf(sp, 1e-10f), 10000.f);
    *sso = sqrtf(sp);
  }
}

// 128x128 GEMM, BK=64, 4 waves (2x2 quads of 64x64), double-buffered LDS
// (64 KiB -> 2 independent blocks/CU). Per tile: issue STAGE(t+1 -> other buf)
// FIRST, then ds_read + 32 MFMA on current buf, then vmcnt(0) (loads hidden
// under the tile's compute) + ONE barrier. XOR swizzle on BOTH global source
// and ds_read address (rule #21); LDS writes linear for global_load_lds.
// Epilogue: per-wave LDS transpose of the finished 64x64 quadrant, then
// nontemporal global_store_dwordx4 (256B contiguous row segments, L2 bypass).
__global__ __launch_bounds__(256, 2) void cauchy_gemm(
    const ushort* __restrict__ xb, const ushort* __restrict__ yb,
    const float* __restrict__ sqx, const float* __restrict__ sqy,
    const float* __restrict__ ssx, const float* __restrict__ ssy,
    const float* __restrict__ cutoff, const float* __restrict__ phi,
    float* __restrict__ out)
{
  __shared__ ushort smem[4 * BM * BK];   // As0|As1|Bs0|Bs1 = 64 KiB

  const int tid  = threadIdx.x;
  const int lane = tid & 63;
  const int w    = tid >> 6;
  const int wr = w >> 1, wc = w & 1;
  const int l15 = lane & 15, l16 = lane >> 4;

  // bijective XCD swizzle: 2048 blocks = 8 XCDs x 256-block chunks.
  // Within a chunk: by sweeps fastest -> yb panel set stays L2-resident.
  const int bid  = blockIdx.x;
  const int sbid = (bid & 7) * 256 + (bid >> 3);
  const int bx = sbid >> 5;      // 64 row-blocks
  const int by = sbid & 31;      // 32 col-blocks

  // ---- staging geometry: 1024 granules (16B) per matrix tile, 4/thread ----
  const ushort* aG[4]; const ushort* bG[4]; int dG[4];
  #pragma unroll
  for (int c = 0; c < 4; c++) {
    int idx = c * 256 + tid;
    int row = idx >> 3, g = idx & 7;
    int sg = g ^ (row & 7);                       // pre-swizzled source granule
    aG[c] = xb + (size_t)(bx * BM + row) * DDIM + sg * 8;
    bG[c] = yb + (size_t)(by * BN + row) * DDIM + sg * 8;
    dG[c] = idx * 8;                              // linear LDS dest (elements)
  }

  // ---- fragment ds_read bases (loop-invariant) ----
  int aRow[4], bRow[4];
  #pragma unroll
  for (int a = 0; a < 4; a++) aRow[a] = wr * 64 + a * 16 + l15;
  #pragma unroll
  for (int b = 0; b < 4; b++) bRow[b] = wc * 64 + b * 16 + l15;

  f32x4 acc[4][4];
  #pragma unroll
  for (int a = 0; a < 4; a++)
    #pragma unroll
    for (int b = 0; b < 4; b++) acc[a][b] = (f32x4)(0.f);

  // ---- prologue: stage tile 0 into buf 0, drain, barrier ----
  #pragma unroll
  for (int c = 0; c < 4; c++) {
    load_lds16(aG[c], &smem[dG[c]]);
    load_lds16(bG[c], &smem[16384 + dG[c]]);
  }
  asm volatile("s_waitcnt vmcnt(0)" ::: "memory");
  __builtin_amdgcn_s_barrier();

  #pragma unroll
  for (int t = 0; t < NT; ++t) {
    const int cur = t & 1, nxt = cur ^ 1;
    if (t + 1 < NT) {   // stage tile t+1 into the other buffer (issue-first)
      #pragma unroll
      for (int c = 0; c < 4; c++) {
        load_lds16(aG[c] + (t + 1) * BK, &smem[nxt * 8192 + dG[c]]);
        load_lds16(bG[c] + (t + 1) * BK, &smem[16384 + nxt * 8192 + dG[c]]);
      }
    }
    const ushort* Ab = smem + cur * 8192;
    const ushort* Bb = smem + 16384 + cur * 8192;
    bf16x8 af[2][4], bf[2][4];
    #pragma unroll
    for (int kk = 0; kk < 2; kk++) {
      #pragma unroll
      for (int a = 0; a < 4; a++)
        af[kk][a] = *(const bf16x8*)&Ab[aRow[a] * 64 + (((kk * 4 + l16) ^ (aRow[a] & 7)) << 3)];
      #pragma unroll
      for (int b = 0; b < 4; b++)
        bf[kk][b] = *(const bf16x8*)&Bb[bRow[b] * 64 + (((kk * 4 + l16) ^ (bRow[b] & 7)) << 3)];
    }
    __builtin_amdgcn_s_setprio(1);
    #pragma unroll
    for (int kk = 0; kk < 2; kk++)
      #pragma unroll
      for (int a = 0; a < 4; a++)
        #pragma unroll
        for (int b = 0; b < 4; b++)
          acc[a][b] = __builtin_amdgcn_mfma_f32_16x16x32_bf16(af[kk][a], bf[kk][b], acc[a][b], 0, 0, 0);
    __builtin_amdgcn_s_setprio(0);
    asm volatile("s_waitcnt vmcnt(0)" ::: "memory");  // t+1 landed (hidden under MFMA)
    __builtin_amdgcn_s_barrier();
  }

  // ---- fused epilogue: compute, LDS-transpose per wave, nt dwordx4 stores ----
  const float cut_c = fminf(fmaxf(cutoff[0], 0.f), 1000.f);
  const float ph = phi[0];
  const int rowBase = bx * BM + wr * 64;
  const int colBase = by * BN + wc * 64;
  const float L2E = 1.4426950408889634f;

  float sq_j[4], sy_j[4];
  #pragma unroll
  for (int b = 0; b < 4; b++) {
    int j = colBase + b * 16 + l15;
    sq_j[b] = sqy[j];
    sy_j[b] = ssy[j];
  }

  // per-wave scratch: 32 rows x 68 floats (8704 B x 4 waves = 34 KiB, LDS dead)
  float* Q = (float*)smem + w * (32 * 68);

  #pragma unroll
  for (int pass = 0; pass < 2; pass++) {
    if (pass == 1) {  // WAR guard: pass-0 reads done before pass-1 writes
      asm volatile("s_waitcnt lgkmcnt(0)" ::: "memory");
      __builtin_amdgcn_sched_barrier(0);
    }
    #pragma unroll
    for (int a2 = 0; a2 < 2; a2++) {
      const int a = pass * 2 + a2;
      float sq_i[4], sx_i[4];
      #pragma unroll
      for (int r = 0; r < 4; r++) {
        int i = rowBase + a * 16 + l16 * 4 + r;
        sq_i[r] = sqx[i];
        sx_i[r] = ssx[i];
      }
      #pragma unroll
      for (int b = 0; b < 4; b++) {
        #pragma unroll
        for (int r = 0; r < 4; r++) {
          float dot = acc[a][b][r];
          float d = sq_i[r] + sq_j[b] - 2.f * dot;       // squared distance
          float s = sx_i[r] * sy_j[b];                   // sqrt(scale_x*scale_y)
          float res = s * __builtin_amdgcn_rcpf(s + d);  // 1/(1+d/s)
          float t2 = ph * (res - cut_c);
          float u = __builtin_amdgcn_exp2f(-t2 * L2E);   // exp(-t)
          float cm = __builtin_amdgcn_rcpf(1.f + u);     // sigmoid(t)
          int lr = a2 * 16 + l16 * 4 + r;
          Q[lr * 68 + b * 16 + l15] = res * cm;          // ds_write_b32
        }
      }
    }
    asm volatile("s_waitcnt lgkmcnt(0)" ::: "memory");   // writes landed
    __builtin_amdgcn_sched_barrier(0);
    #pragma unroll
    for (int g = 0; g < 8; g++) {
      int lr = g * 4 + l16;
      f32x4 v = *(const f32x4*)&Q[lr * 68 + 4 * l15];
      int i = rowBase + pass * 32 + lr;
      __builtin_nontemporal_store(
          v, (f32x4*)(out + (size_t)i * M_ROWS + colBase + 4 * l15));
    }
  }
}

extern "C" void kernel_launch(void* const* d_in, const int* in_sizes, int n_in,
                              void* d_out, int out_size, void* d_ws, size_t ws_size,
                              hipStream_t stream) {
  const float* x       = (const float*)d_in[0];
  const float* y       = (const float*)d_in[1];
  const float* samp_x  = (const float*)d_in[2];
  const float* samp_y  = (const float*)d_in[3];
  const float* scale   = (const float*)d_in[4];
  const float* cutoff  = (const float*)d_in[5];
  const float* phi     = (const float*)d_in[6];
  float* out = (float*)d_out;

  char* p = (char*)d_ws;
  ushort* xb = (ushort*)p; p += (size_t)N_ROWS * DDIM * 2;
  ushort* yb = (ushort*)p; p += (size_t)M_ROWS * DDIM * 2;
  float* sqx = (float*)p;  p += (size_t)N_ROWS * 4;
  float* sqy = (float*)p;  p += (size_t)M_ROWS * 4;
  float* ssx = (float*)p;  p += (size_t)N_ROWS * 4;
  float* ssy = (float*)p;  p += (size_t)M_ROWS * 4;

  prep_kernel<<<N_ROWS + M_ROWS, 256, 0, stream>>>(
      x, y, samp_x, samp_y, scale, xb, yb, sqx, sqy, ssx, ssy);

  cauchy_gemm<<<(N_ROWS / BM) * (M_ROWS / BN), 256, 0, stream>>>(
      xb, yb, sqx, sqy, ssx, ssy, cutoff, phi, out);
}